// Round 8
// baseline (865.770 us; speedup 1.0000x reference)
//
#include <hip/hip_runtime.h>

typedef __attribute__((ext_vector_type(8))) short short8;
typedef __attribute__((ext_vector_type(4))) float floatx4;

// ---------- helpers ----------
__device__ __forceinline__ unsigned short f2bf(float f) {
  union { float f; unsigned u; } x; x.f = f;
  unsigned u = x.u + 0x7fffu + ((x.u >> 16) & 1u);   // RNE
  return (unsigned short)(u >> 16);
}

__device__ __forceinline__ void gload_lds16(const void* g, void* l) {
  __builtin_amdgcn_global_load_lds(
      (const __attribute__((address_space(1))) unsigned int*)g,
      (__attribute__((address_space(3))) unsigned int*)l, 16, 0, 0);
}

// ---------- constants ----------
// B=8, H=W=128, DIM=512, NH=8, HD=64, K=7, R=3
// M = 131072 rows; GEMM: [M,512] x [512,1024] -> [M,1024]

// ---------- kernel 1: convert x fp32 -> bf16 ----------
__global__ __launch_bounds__(256) void cvt_x(const float4* __restrict__ x,
                                             uint2* __restrict__ o) {
  size_t idx = (size_t)blockIdx.x * 256 + threadIdx.x;
  float4 v = x[idx];
  uint2 r;
  r.x = (unsigned)f2bf(v.x) | ((unsigned)f2bf(v.y) << 16);
  r.y = (unsigned)f2bf(v.z) | ((unsigned)f2bf(v.w) << 16);
  o[idx] = r;
}

// ---------- kernel 2: convert + transpose W (fold q scale) ----------
__global__ __launch_bounds__(256) void cvt_w(const float* __restrict__ w,
                                             unsigned short* __restrict__ wt) {
  int tid = blockIdx.x * 256 + threadIdx.x;
  int n = tid >> 9, k = tid & 511;
  float v = w[k * 1024 + n];
  if (n < 512) v *= 0.125f;
  wt[tid] = f2bf(v);
}

// ---------- kernel 3: bf16 MFMA GEMM, 256x256, BK=32, ring-4, FREE-RUNNING ----------
// ONE rendezvous per K-tile: {vmcnt(8)+s_barrier; stage kt+3; 12 ds_reads; 32 MFMA}.
// No intra-tile barriers: the 2 waves/SIMD self-overlap (one wave's ds_reads run
// under the other's MFMA cluster). WAR safety: a wave's tile-kt ds_reads complete
// before it passes the kt+1 barrier (its MFMAs consume them, lgkmcnt-gated), and
// stage(kt+3) is issued only after that barrier, into slot (kt-1)&3.
__global__ __launch_bounds__(512, 2) void gemm_bt(const unsigned short* __restrict__ A,
                                                  const unsigned short* __restrict__ Bt,
                                                  unsigned short* __restrict__ C) {
  __shared__ __align__(16) unsigned short lds_a[4][8192];   // ring-4, [kg][row][8] 16 KB
  __shared__ __align__(16) unsigned short lds_b[4][8192];

  const int t = threadIdx.x;                     // 0..511
  const int bid = blockIdx.x;                    // 2048 blocks, 2048 % 8 == 0
  const int wg = (bid & 7) * 256 + (bid >> 3);   // XCD-contiguous chunks
  const int mtile = wg >> 2;                     // 512 m-tiles
  const int ntile = wg & 3;                      // 4 n-tiles share A-tile in L2
  const int m0 = mtile * 256, n0 = ntile * 256;
  const int wave = t >> 6, lane = t & 63;
  const int wr = wave >> 2, wc = wave & 3;       // 2M x 4N waves, 128x64 each
  const int kg = lane >> 4, rr = lane & 15;

  // staging coords: load l in {0,1}, S = t + l*512, kgrp = S>>8, row = S&255
  const unsigned short* aP[2];
  const unsigned short* bP[2];
#pragma unroll
  for (int l = 0; l < 2; ++l) {
    int S = t + l * 512, kgrp = S >> 8, row = S & 255;
    aP[l] = &A[(size_t)(m0 + row) * 512 + kgrp * 8];
    bP[l] = &Bt[(size_t)(n0 + row) * 512 + kgrp * 8];
  }

  // prologue: stage tiles 0,1,2 into bufs 0,1,2  (12 loads/thread in flight)
#pragma unroll
  for (int tt = 0; tt < 3; ++tt)
#pragma unroll
    for (int l = 0; l < 2; ++l) {
      gload_lds16(aP[l] + tt * 32, &lds_a[tt][(t + l * 512) * 8]);
      gload_lds16(bP[l] + tt * 32, &lds_b[tt][(t + l * 512) * 8]);
    }

  floatx4 acc[8][4] = {};

#pragma unroll
  for (int kt = 0; kt < 16; ++kt) {
    const int cur = kt & 3;
    // tile kt landed; tiles kt+1, kt+2 (8 loads) stay in flight
    if (kt <= 13)
      asm volatile("s_waitcnt vmcnt(8)\n\ts_barrier" ::: "memory");
    else if (kt == 14)
      asm volatile("s_waitcnt vmcnt(4)\n\ts_barrier" ::: "memory");
    else
      asm volatile("s_waitcnt vmcnt(0)\n\ts_barrier" ::: "memory");

    // stage tile kt+3 into buf (kt+3)&3 = (kt-1)&3 (readers done before this barrier)
    if (kt <= 12) {
      const int nb = (kt + 3) & 3, k0n = (kt + 3) * 32;
#pragma unroll
      for (int l = 0; l < 2; ++l) {
        gload_lds16(aP[l] + k0n, &lds_a[nb][(t + l * 512) * 8]);
        gload_lds16(bP[l] + k0n, &lds_b[nb][(t + l * 512) * 8]);
      }
    }

    // fragments + MFMA, free-running (no further barriers this tile)
    short8 af[8], bf[4];
#pragma unroll
    for (int i = 0; i < 8; ++i)
      af[i] = *(const short8*)&lds_a[cur][(kg * 256 + wr * 128 + i * 16 + rr) * 8];
#pragma unroll
    for (int j = 0; j < 4; ++j)
      bf[j] = *(const short8*)&lds_b[cur][(kg * 256 + wc * 64 + j * 16 + rr) * 8];
    __builtin_amdgcn_s_setprio(1);
#pragma unroll
    for (int i = 0; i < 8; ++i)
#pragma unroll
      for (int j = 0; j < 4; ++j)
        acc[i][j] = __builtin_amdgcn_mfma_f32_16x16x32_bf16(af[i], bf[j], acc[i][j], 0, 0, 0);
    __builtin_amdgcn_s_setprio(0);
  }

  // ---- epilogue: wave-private LDS staging, then dense uint4 wave-stores ----
  __syncthreads();
  unsigned short* cst = (wave < 4) ? &lds_a[wave][0] : &lds_b[wave - 4][0];  // 8192 shorts
  // acc C/D layout (verified m89): col = rr, row = i*16 + kg*4 + r
#pragma unroll
  for (int i = 0; i < 8; ++i)
#pragma unroll
    for (int j = 0; j < 4; ++j)
#pragma unroll
      for (int r = 0; r < 4; ++r)
        cst[(i * 16 + kg * 4 + r) * 64 + j * 16 + rr] = f2bf(acc[i][j][r]);
  asm volatile("s_waitcnt lgkmcnt(0)" ::: "memory");
  {
    unsigned short* Cg = C + (size_t)(m0 + wr * 128) * 1024 + n0 + wc * 64;
#pragma unroll
    for (int p = 0; p < 16; ++p) {
      int idx = p * 64 + lane;
      int lr = idx >> 3, g8 = idx & 7;
      uint4 v = *(const uint4*)&cst[lr * 64 + g8 * 8];
      *(uint4*)&Cg[(size_t)lr * 1024 + g8 * 8] = v;
    }
  }
}

// ---------- kernel 4: MFMA banded neighborhood-attention logits ----------
// Direct lane->out_lds scatter: lane (kg,rr) holds S[pixel kg*4+r][kcol rr (acc0) /
// 16+rr (acc1)]; kj = kcol - relc(p). No scratch, no lgkm drains in the loop.
__global__ __launch_bounds__(256) void attn_mfma(const unsigned short* __restrict__ QK,
                                                 float* __restrict__ out) {
  __shared__ __align__(16) unsigned short q_lds[128 * 64];      // 16 KB [j][grp^swz]
  __shared__ __align__(16) unsigned short k_lds[2][128 * 64];   // 32 KB [c][grp^swz]
  __shared__ __align__(16) float out_lds[128 * 49];             // 24.5 KB
  // total = 74240 B -> 2 blocks/CU

  const int t = threadIdx.x;
  const int bid = blockIdx.x;                   // 8192 = 8b*8h*128i
  const int wg = (bid & 7) * 1024 + (bid >> 3); // XCD-contiguous: i-neighbors share k rows in L2
  const int i = wg & 127;
  const int h = (wg >> 7) & 7;
  const int b = wg >> 10;
  const int wave = t >> 6, lane = t & 63;
  const int kg = lane >> 4, rr = lane & 15;
  const int ri = min(max(i - 3, 0), 121);

  // issue q row (4 insts), then k rows ki=0 (4) and ki=1 (4): 12 vmem insts in flight
  const unsigned short* qbase = QK + ((size_t)(b * 128 + i) * 128) * 1024 + h * 64;
#pragma unroll
  for (int s = 0; s < 4; ++s) {
    int S = t + s * 256;                        // 0..1023
    int j = S >> 3, pg = S & 7, lg = pg ^ (j & 7);
    gload_lds16(qbase + (size_t)j * 1024 + lg * 8, &q_lds[S * 8]);
  }
#pragma unroll
  for (int kt = 0; kt < 2; ++kt) {
    const unsigned short* kb = QK + ((size_t)(b * 128 + ri + kt) * 128) * 1024 + 512 + h * 64;
#pragma unroll
    for (int s = 0; s < 4; ++s) {
      int S = t + s * 256;
      int c = S >> 3, pg = S & 7, lg = pg ^ (c & 7);
      gload_lds16(kb + (size_t)c * 1024 + lg * 8, &k_lds[kt][S * 8]);
    }
  }

  // q ready (oldest 4 insts); k0/k1 stay in flight
  asm volatile("s_waitcnt vmcnt(8)\n\ts_barrier" ::: "memory");

  // hoist q fragments: wave owns jtiles 2w, 2w+1.  A-frag: row=lane&15, k=(lane>>4)*8
  short8 af[2][2];
#pragma unroll
  for (int jt2 = 0; jt2 < 2; ++jt2) {
    int row = (wave * 2 + jt2) * 16 + rr;
#pragma unroll
    for (int ks = 0; ks < 2; ++ks) {
      int lg = ks * 4 + kg;
      af[jt2][ks] = *(const short8*)&q_lds[(row * 8 + (lg ^ (row & 7))) * 8];
    }
  }

#pragma unroll
  for (int ki = 0; ki < 7; ++ki) {
    // wait for k_ki only (k_{ki+1}'s 4 insts stay in flight), rendezvous
    if (ki < 6)
      asm volatile("s_waitcnt vmcnt(4)\n\ts_barrier" ::: "memory");
    else
      asm volatile("s_waitcnt vmcnt(0)\n\ts_barrier" ::: "memory");

    const unsigned short* kbuf = k_lds[ki & 1];

#pragma unroll
    for (int jt2 = 0; jt2 < 2; ++jt2) {
      const int j0 = (wave * 2 + jt2) * 16;
      const int cb = min(max(j0 - 3, 0), 121);  // col base; needed rel cols 0..21
      const int c0 = min(cb + rr, 127);         // clamp: clamped lanes never pass guard
      const int c1 = min(cb + 16 + rr, 127);
      floatx4 acc0 = {0.f, 0.f, 0.f, 0.f}, acc1 = {0.f, 0.f, 0.f, 0.f};
      __builtin_amdgcn_s_setprio(1);
#pragma unroll
      for (int ks = 0; ks < 2; ++ks) {
        int lg = ks * 4 + kg;
        short8 b0 = *(const short8*)&kbuf[(c0 * 8 + (lg ^ (c0 & 7))) * 8];
        short8 b1 = *(const short8*)&kbuf[(c1 * 8 + (lg ^ (c1 & 7))) * 8];
        acc0 = __builtin_amdgcn_mfma_f32_16x16x32_bf16(af[jt2][ks], b0, acc0, 0, 0, 0);
        acc1 = __builtin_amdgcn_mfma_f32_16x16x32_bf16(af[jt2][ks], b1, acc1, 0, 0, 0);
      }
      __builtin_amdgcn_s_setprio(0);
      // direct scatter: acc row = kg*4 + r (pixel), acc0 col = rr, acc1 col = 16+rr
#pragma unroll
      for (int r = 0; r < 4; ++r) {
        int p = j0 + kg * 4 + r;
        int relc = min(max(p - 3, 0), 121) - cb;       // 0..15
        int k0a = rr - relc;
        if ((unsigned)k0a < 7u) out_lds[p * 49 + ki * 7 + k0a] = acc0[r];
        int k1a = 16 + rr - relc;
        if ((unsigned)k1a < 7u) out_lds[p * 49 + ki * 7 + k1a] = acc1[r];
      }
    }

    // all waves done reading k_lds[ki&1] -> safe to re-issue into it
    asm volatile("s_barrier" ::: "memory");
    if (ki + 2 <= 6) {
      const unsigned short* kb =
          QK + ((size_t)(b * 128 + ri + ki + 2) * 128) * 1024 + 512 + h * 64;
#pragma unroll
      for (int s = 0; s < 4; ++s) {
        int S = t + s * 256;
        int c = S >> 3, pg = S & 7, lg = pg ^ (c & 7);
        gload_lds16(kb + (size_t)c * 1024 + lg * 8, &k_lds[ki & 1][S * 8]);
      }
    }
  }

  // coalesced flush: 128*49 floats = 25088 B contiguous per (b,h,i)
  __syncthreads();   // all waves' out_lds scatters visible
  const uint4* src = (const uint4*)out_lds;
  uint4* dst = (uint4*)(out + ((size_t)(b * 8 + h) * 16384 + (size_t)i * 128) * 49);
  for (int s = t; s < 1568; s += 256) dst[s] = src[s];
}

// ---------- launch ----------
extern "C" void kernel_launch(void* const* d_in, const int* in_sizes, int n_in,
                              void* d_out, int out_size, void* d_ws, size_t ws_size,
                              hipStream_t stream) {
  const float* x = (const float*)d_in[0];
  const float* w = (const float*)d_in[1];
  float* out = (float*)d_out;

  unsigned short* xb = (unsigned short*)d_ws;        // 67,108,864 shorts
  unsigned short* wt = xb + 67108864;                // 524,288
  unsigned short* qk = wt + 524288;                  // 134,217,728

  cvt_x<<<65536, 256, 0, stream>>>((const float4*)x, (uint2*)xb);
  cvt_w<<<2048, 256, 0, stream>>>(w, wt);
  gemm_bt<<<2048, 512, 0, stream>>>(xb, wt, qk);
  attn_mfma<<<8192, 256, 0, stream>>>(qk, out);
}

// Round 9
// 798.001 us; speedup vs baseline: 1.0849x; 1.0849x over previous
//
#include <hip/hip_runtime.h>

typedef __attribute__((ext_vector_type(8))) short short8;
typedef __attribute__((ext_vector_type(4))) float floatx4;

// ---------- helpers ----------
__device__ __forceinline__ unsigned short f2bf(float f) {
  union { float f; unsigned u; } x; x.f = f;
  unsigned u = x.u + 0x7fffu + ((x.u >> 16) & 1u);   // RNE
  return (unsigned short)(u >> 16);
}

__device__ __forceinline__ void gload_lds16(const void* g, void* l) {
  __builtin_amdgcn_global_load_lds(
      (const __attribute__((address_space(1))) unsigned int*)g,
      (__attribute__((address_space(3))) unsigned int*)l, 16, 0, 0);
}

// ---------- constants ----------
// B=8, H=W=128, DIM=512, NH=8, HD=64, K=7, R=3
// M = 131072 rows; GEMM: [M,512] x [512,1024] -> [M,1024]

// ---------- kernel 1: convert x fp32 -> bf16 ----------
__global__ __launch_bounds__(256) void cvt_x(const float4* __restrict__ x,
                                             uint2* __restrict__ o) {
  size_t idx = (size_t)blockIdx.x * 256 + threadIdx.x;
  float4 v = x[idx];
  uint2 r;
  r.x = (unsigned)f2bf(v.x) | ((unsigned)f2bf(v.y) << 16);
  r.y = (unsigned)f2bf(v.z) | ((unsigned)f2bf(v.w) << 16);
  o[idx] = r;
}

// ---------- kernel 2: convert + transpose W (fold q scale) ----------
__global__ __launch_bounds__(256) void cvt_w(const float* __restrict__ w,
                                             unsigned short* __restrict__ wt) {
  int tid = blockIdx.x * 256 + threadIdx.x;
  int n = tid >> 9, k = tid & 511;
  float v = w[k * 1024 + n];
  if (n < 512) v *= 0.125f;
  wt[tid] = f2bf(v);
}

// ---------- kernel 3: bf16 MFMA GEMM, 256x256, BK=32, ring-4, PHASE-SPLIT ----------
// R7 skeleton (verified 290 us; free-running R8 regressed to 350 -> barriers are
// the lever). Balanced phases: A = {stage-A + 8 ds_reads | bar | 16 MFMA i=0..3},
// B = {stage-B + 4 ds_reads | bar | 16 MFMA i=4..7}. Counted vmcnt(8) at tile top
// only; 2 tiles of loads always in flight.
__global__ __launch_bounds__(512, 2) void gemm_bt(const unsigned short* __restrict__ A,
                                                  const unsigned short* __restrict__ Bt,
                                                  unsigned short* __restrict__ C) {
  __shared__ __align__(16) unsigned short lds_a[4][8192];   // ring-4, [kg][row][8] 16 KB
  __shared__ __align__(16) unsigned short lds_b[4][8192];

  const int t = threadIdx.x;                     // 0..511
  const int bid = blockIdx.x;                    // 2048 blocks, 2048 % 8 == 0
  const int wg = (bid & 7) * 256 + (bid >> 3);   // XCD-contiguous chunks
  const int mtile = wg >> 2;                     // 512 m-tiles
  const int ntile = wg & 3;                      // 4 n-tiles share A-tile in L2
  const int m0 = mtile * 256, n0 = ntile * 256;
  const int wave = t >> 6, lane = t & 63;
  const int wr = wave >> 2, wc = wave & 3;       // 2M x 4N waves, 128x64 each
  const int kg = lane >> 4, rr = lane & 15;

  // staging coords: load l in {0,1}, S = t + l*512, kgrp = S>>8, row = S&255
  const unsigned short* aP[2];
  const unsigned short* bP[2];
#pragma unroll
  for (int l = 0; l < 2; ++l) {
    int S = t + l * 512, kgrp = S >> 8, row = S & 255;
    aP[l] = &A[(size_t)(m0 + row) * 512 + kgrp * 8];
    bP[l] = &Bt[(size_t)(n0 + row) * 512 + kgrp * 8];
  }

  // prologue: stage tiles 0,1,2 into bufs 0,1,2  (12 loads/thread in flight)
#pragma unroll
  for (int tt = 0; tt < 3; ++tt)
#pragma unroll
    for (int l = 0; l < 2; ++l) {
      gload_lds16(aP[l] + tt * 32, &lds_a[tt][(t + l * 512) * 8]);
      gload_lds16(bP[l] + tt * 32, &lds_b[tt][(t + l * 512) * 8]);
    }

  floatx4 acc[8][4] = {};

#pragma unroll
  for (int kt = 0; kt < 16; ++kt) {
    const int cur = kt & 3;
    // tile kt landed; tiles kt+1, kt+2 (8 loads) stay in flight
    if (kt <= 13)
      asm volatile("s_waitcnt vmcnt(8)\n\ts_barrier" ::: "memory");
    else if (kt == 14)
      asm volatile("s_waitcnt vmcnt(4)\n\ts_barrier" ::: "memory");
    else
      asm volatile("s_waitcnt vmcnt(0)\n\ts_barrier" ::: "memory");

    short8 af[8], bf[4];
    // ---- phase A: ds_reads af[0..3] + bf[0..3] (8) + stage A(kt+3) | bar | 16 MFMA | bar
#pragma unroll
    for (int i = 0; i < 4; ++i)
      af[i] = *(const short8*)&lds_a[cur][(kg * 256 + wr * 128 + i * 16 + rr) * 8];
#pragma unroll
    for (int j = 0; j < 4; ++j)
      bf[j] = *(const short8*)&lds_b[cur][(kg * 256 + wc * 64 + j * 16 + rr) * 8];
    if (kt <= 12) {
      const int nb = (kt + 3) & 3, k0n = (kt + 3) * 32;
#pragma unroll
      for (int l = 0; l < 2; ++l)
        gload_lds16(aP[l] + k0n, &lds_a[nb][(t + l * 512) * 8]);
    }
    asm volatile("s_barrier" ::: "memory");
    __builtin_amdgcn_s_setprio(1);
#pragma unroll
    for (int i = 0; i < 4; ++i)
#pragma unroll
      for (int j = 0; j < 4; ++j)
        acc[i][j] = __builtin_amdgcn_mfma_f32_16x16x32_bf16(af[i], bf[j], acc[i][j], 0, 0, 0);
    __builtin_amdgcn_s_setprio(0);
    asm volatile("s_barrier" ::: "memory");

    // ---- phase B: ds_reads af[4..7] (4) + stage B(kt+3) | bar | 16 MFMA | bar
#pragma unroll
    for (int i = 4; i < 8; ++i)
      af[i] = *(const short8*)&lds_a[cur][(kg * 256 + wr * 128 + i * 16 + rr) * 8];
    if (kt <= 12) {
      const int nb = (kt + 3) & 3, k0n = (kt + 3) * 32;
#pragma unroll
      for (int l = 0; l < 2; ++l)
        gload_lds16(bP[l] + k0n, &lds_b[nb][(t + l * 512) * 8]);
    }
    asm volatile("s_barrier" ::: "memory");
    __builtin_amdgcn_s_setprio(1);
#pragma unroll
    for (int i = 4; i < 8; ++i)
#pragma unroll
      for (int j = 0; j < 4; ++j)
        acc[i][j] = __builtin_amdgcn_mfma_f32_16x16x32_bf16(af[i], bf[j], acc[i][j], 0, 0, 0);
    __builtin_amdgcn_s_setprio(0);
    asm volatile("s_barrier" ::: "memory");
  }

  // ---- epilogue: wave-private LDS staging, then dense uint4 wave-stores ----
  __syncthreads();
  unsigned short* cst = (wave < 4) ? &lds_a[wave][0] : &lds_b[wave - 4][0];  // 8192 shorts
  // acc C/D layout (verified m89): col = rr, row = i*16 + kg*4 + r
#pragma unroll
  for (int i = 0; i < 8; ++i)
#pragma unroll
    for (int j = 0; j < 4; ++j)
#pragma unroll
      for (int r = 0; r < 4; ++r)
        cst[(i * 16 + kg * 4 + r) * 64 + j * 16 + rr] = f2bf(acc[i][j][r]);
  asm volatile("s_waitcnt lgkmcnt(0)" ::: "memory");
  {
    unsigned short* Cg = C + (size_t)(m0 + wr * 128) * 1024 + n0 + wc * 64;
#pragma unroll
    for (int p = 0; p < 16; ++p) {
      int idx = p * 64 + lane;
      int lr = idx >> 3, g8 = idx & 7;
      uint4 v = *(const uint4*)&cst[lr * 64 + g8 * 8];
      *(uint4*)&Cg[(size_t)lr * 1024 + g8 * 8] = v;
    }
  }
}

// ---------- kernel 4: MFMA banded neighborhood-attention logits ----------
// Direct lane->out_lds scatter: lane (kg,rr) holds S[pixel kg*4+r][kcol rr (acc0) /
// 16+rr (acc1)]; kj = kcol - relc(p). No scratch, no lgkm drains in the loop.
__global__ __launch_bounds__(256) void attn_mfma(const unsigned short* __restrict__ QK,
                                                 float* __restrict__ out) {
  __shared__ __align__(16) unsigned short q_lds[128 * 64];      // 16 KB [j][grp^swz]
  __shared__ __align__(16) unsigned short k_lds[2][128 * 64];   // 32 KB [c][grp^swz]
  __shared__ __align__(16) float out_lds[128 * 49];             // 24.5 KB
  // total = 74240 B -> 2 blocks/CU

  const int t = threadIdx.x;
  const int bid = blockIdx.x;                   // 8192 = 8b*8h*128i
  const int wg = (bid & 7) * 1024 + (bid >> 3); // XCD-contiguous: i-neighbors share k rows in L2
  const int i = wg & 127;
  const int h = (wg >> 7) & 7;
  const int b = wg >> 10;
  const int wave = t >> 6, lane = t & 63;
  const int kg = lane >> 4, rr = lane & 15;
  const int ri = min(max(i - 3, 0), 121);

  // issue q row (4 insts), then k rows ki=0 (4) and ki=1 (4): 12 vmem insts in flight
  const unsigned short* qbase = QK + ((size_t)(b * 128 + i) * 128) * 1024 + h * 64;
#pragma unroll
  for (int s = 0; s < 4; ++s) {
    int S = t + s * 256;                        // 0..1023
    int j = S >> 3, pg = S & 7, lg = pg ^ (j & 7);
    gload_lds16(qbase + (size_t)j * 1024 + lg * 8, &q_lds[S * 8]);
  }
#pragma unroll
  for (int kt = 0; kt < 2; ++kt) {
    const unsigned short* kb = QK + ((size_t)(b * 128 + ri + kt) * 128) * 1024 + 512 + h * 64;
#pragma unroll
    for (int s = 0; s < 4; ++s) {
      int S = t + s * 256;
      int c = S >> 3, pg = S & 7, lg = pg ^ (c & 7);
      gload_lds16(kb + (size_t)c * 1024 + lg * 8, &k_lds[kt][S * 8]);
    }
  }

  // q ready (oldest 4 insts); k0/k1 stay in flight
  asm volatile("s_waitcnt vmcnt(8)\n\ts_barrier" ::: "memory");

  // hoist q fragments: wave owns jtiles 2w, 2w+1.  A-frag: row=lane&15, k=(lane>>4)*8
  short8 af[2][2];
#pragma unroll
  for (int jt2 = 0; jt2 < 2; ++jt2) {
    int row = (wave * 2 + jt2) * 16 + rr;
#pragma unroll
    for (int ks = 0; ks < 2; ++ks) {
      int lg = ks * 4 + kg;
      af[jt2][ks] = *(const short8*)&q_lds[(row * 8 + (lg ^ (row & 7))) * 8];
    }
  }

#pragma unroll
  for (int ki = 0; ki < 7; ++ki) {
    // wait for k_ki only (k_{ki+1}'s 4 insts stay in flight), rendezvous
    if (ki < 6)
      asm volatile("s_waitcnt vmcnt(4)\n\ts_barrier" ::: "memory");
    else
      asm volatile("s_waitcnt vmcnt(0)\n\ts_barrier" ::: "memory");

    const unsigned short* kbuf = k_lds[ki & 1];

#pragma unroll
    for (int jt2 = 0; jt2 < 2; ++jt2) {
      const int j0 = (wave * 2 + jt2) * 16;
      const int cb = min(max(j0 - 3, 0), 121);  // col base; needed rel cols 0..21
      const int c0 = min(cb + rr, 127);         // clamp: clamped lanes never pass guard
      const int c1 = min(cb + 16 + rr, 127);
      floatx4 acc0 = {0.f, 0.f, 0.f, 0.f}, acc1 = {0.f, 0.f, 0.f, 0.f};
      __builtin_amdgcn_s_setprio(1);
#pragma unroll
      for (int ks = 0; ks < 2; ++ks) {
        int lg = ks * 4 + kg;
        short8 b0 = *(const short8*)&kbuf[(c0 * 8 + (lg ^ (c0 & 7))) * 8];
        short8 b1 = *(const short8*)&kbuf[(c1 * 8 + (lg ^ (c1 & 7))) * 8];
        acc0 = __builtin_amdgcn_mfma_f32_16x16x32_bf16(af[jt2][ks], b0, acc0, 0, 0, 0);
        acc1 = __builtin_amdgcn_mfma_f32_16x16x32_bf16(af[jt2][ks], b1, acc1, 0, 0, 0);
      }
      __builtin_amdgcn_s_setprio(0);
      // direct scatter: acc row = kg*4 + r (pixel), acc0 col = rr, acc1 col = 16+rr
#pragma unroll
      for (int r = 0; r < 4; ++r) {
        int p = j0 + kg * 4 + r;
        int relc = min(max(p - 3, 0), 121) - cb;       // 0..15
        int k0a = rr - relc;
        if ((unsigned)k0a < 7u) out_lds[p * 49 + ki * 7 + k0a] = acc0[r];
        int k1a = 16 + rr - relc;
        if ((unsigned)k1a < 7u) out_lds[p * 49 + ki * 7 + k1a] = acc1[r];
      }
    }

    // all waves done reading k_lds[ki&1] -> safe to re-issue into it
    asm volatile("s_barrier" ::: "memory");
    if (ki + 2 <= 6) {
      const unsigned short* kb =
          QK + ((size_t)(b * 128 + ri + ki + 2) * 128) * 1024 + 512 + h * 64;
#pragma unroll
      for (int s = 0; s < 4; ++s) {
        int S = t + s * 256;
        int c = S >> 3, pg = S & 7, lg = pg ^ (c & 7);
        gload_lds16(kb + (size_t)c * 1024 + lg * 8, &k_lds[ki & 1][S * 8]);
      }
    }
  }

  // coalesced flush: 128*49 floats = 25088 B contiguous per (b,h,i)
  __syncthreads();   // all waves' out_lds scatters visible
  const uint4* src = (const uint4*)out_lds;
  uint4* dst = (uint4*)(out + ((size_t)(b * 8 + h) * 16384 + (size_t)i * 128) * 49);
  for (int s = t; s < 1568; s += 256) dst[s] = src[s];
}

// ---------- launch ----------
extern "C" void kernel_launch(void* const* d_in, const int* in_sizes, int n_in,
                              void* d_out, int out_size, void* d_ws, size_t ws_size,
                              hipStream_t stream) {
  const float* x = (const float*)d_in[0];
  const float* w = (const float*)d_in[1];
  float* out = (float*)d_out;

  unsigned short* xb = (unsigned short*)d_ws;        // 67,108,864 shorts
  unsigned short* wt = xb + 67108864;                // 524,288
  unsigned short* qk = wt + 524288;                  // 134,217,728

  cvt_x<<<65536, 256, 0, stream>>>((const float4*)x, (uint2*)xb);
  cvt_w<<<2048, 256, 0, stream>>>(w, wt);
  gemm_bt<<<2048, 512, 0, stream>>>(xb, wt, qk);
  attn_mfma<<<8192, 256, 0, stream>>>(qk, out);
}